// Round 1
// baseline (165.423 us; speedup 1.0000x reference)
//
#include <hip/hip_runtime.h>
#include <hip/hip_bf16.h>

// FirDownsample: y = depthwise FIR(4x4 separable [1,3,3,1]/8 outer) on x (pad 2),
// out = conv3x3(y, w), stride 2, VALID.  x:(16,320,64,64) f32, out:(16,320,32,32) f32.
//
// Pipeline (ws >= 45.1 MB):
//   K1 fir_kernel : x -> y_t[n][65][65][320] bf16 (channels-last for MFMA staging)
//   K2 wt_kernel  : w -> wT[tap][co][ci] bf16
//   K3 conv_kernel: MFMA 16x16x32 bf16 GEMM-conv, D[co][m] so stores coalesce.
// Fallback: naive direct kernel (correct, slow) if ws too small.

typedef short s16x4 __attribute__((ext_vector_type(4)));
typedef short bf16x8_t __attribute__((ext_vector_type(8)));
typedef float f32x4 __attribute__((ext_vector_type(4)));
typedef unsigned int u32x2 __attribute__((ext_vector_type(2)));
typedef unsigned int u32x4 __attribute__((ext_vector_type(4)));

#define NI 16
#define CCH 320
#define HW 64
#define HY 65

// ---------------- K1: separable FIR, x(f32) -> y_t bf16 [n][r][c][ci] ----------------
// block: (n, row-band of 8, ci-chunk of 16). vert pass in regs -> LDS, horiz pass -> global.
__global__ __launch_bounds__(256) void fir_kernel(const float* __restrict__ x,
                                                  const float* __restrict__ fir_k,
                                                  __hip_bfloat16* __restrict__ yt) {
    __shared__ float vlds[8 * 68 * 17];  // [j][cc][ci+pad] : 36992 B
    int bx = blockIdx.x;
    int n   = bx / 180;
    int rr  = bx % 180;
    int r0  = (rr / 20) * 8;   // row band start, 0..64
    int ci0 = (rr % 20) * 16;

    // separable factors: f[a] = sum_b k[a][b]  (exact for rank-1 fir_k)
    float f0 = fir_k[0] + fir_k[1] + fir_k[2] + fir_k[3];
    float f1 = fir_k[4] + fir_k[5] + fir_k[6] + fir_k[7];
    float f2 = fir_k[8] + fir_k[9] + fir_k[10] + fir_k[11];
    float f3 = fir_k[12] + fir_k[13] + fir_k[14] + fir_k[15];

    int tid = threadIdx.x;
    int lane = tid & 63;
    int g = tid >> 6;

    // vertical pass: vert[r0+j][w] = sum_a f[a] * x[r0+j-2+a][w]
    for (int cis = g; cis < 16; cis += 4) {
        int ci = ci0 + cis;
        const float* xb = x + (size_t)(n * CCH + ci) * HW * HW;
        float xr[11];
#pragma unroll
        for (int jr = 0; jr < 11; ++jr) {
            int row = r0 + jr - 2;
            xr[jr] = (row >= 0 && row < HW) ? xb[row * HW + lane] : 0.f;
        }
#pragma unroll
        for (int j = 0; j < 8; ++j) {
            float v = f0 * xr[j] + f1 * xr[j + 1] + f2 * xr[j + 2] + f3 * xr[j + 3];
            vlds[(j * 68 + lane + 2) * 17 + cis] = v;           // cc = w+2
            if (lane < 2)   vlds[(j * 68 + lane) * 17 + cis] = 0.f;      // cc 0,1
            if (lane >= 62) vlds[(j * 68 + lane + 4) * 17 + cis] = 0.f;  // cc 66,67
        }
    }
    __syncthreads();

    // horizontal pass: y[r][c] = sum_b f[b] * vert[r][c-2+b] = sum_b f[b]*vlds[c+b]
    int cis = tid & 15;
    int cl  = tid >> 4;  // 0..15
#pragma unroll
    for (int j = 0; j < 8; ++j) {
        if (r0 + j >= HY) break;
        for (int cb = 0; cb < 5; ++cb) {
            int c = cb * 16 + cl;
            if (c < HY) {
                float yv = f0 * vlds[(j * 68 + c) * 17 + cis]
                         + f1 * vlds[(j * 68 + c + 1) * 17 + cis]
                         + f2 * vlds[(j * 68 + c + 2) * 17 + cis]
                         + f3 * vlds[(j * 68 + c + 3) * 17 + cis];
                yt[(size_t)((n * HY + r0 + j) * HY + c) * CCH + ci0 + cis] =
                    __float2bfloat16(yv);
            }
        }
    }
}

// ---------------- K2: w (co,ci,3,3) f32 -> wT[tap][co][ci] bf16 ----------------
__global__ __launch_bounds__(256) void wt_kernel(const float* __restrict__ w,
                                                 __hip_bfloat16* __restrict__ wt) {
    int idx = blockIdx.x * 256 + threadIdx.x;
    if (idx < 9 * CCH * CCH) {
        int tap = idx / (CCH * CCH);
        int r = idx % (CCH * CCH);
        int co = r / CCH, ci = r % CCH;
        wt[idx] = __float2bfloat16(w[(co * CCH + ci) * 9 + tap]);
    }
}

// ---------------- K3: MFMA conv ----------------
// block: n, co-chunk 64, spatial tile 8(oh) x 16(ow) = 128 m.  4 waves, wave = M64 x N32.
// K loop: ci chunks of 32; 9 taps = shifted reads of the y tile (17x33 positions).
__global__ __launch_bounds__(256, 2) void conv_kernel(const __hip_bfloat16* __restrict__ yt,
                                                      const __hip_bfloat16* __restrict__ wtp,
                                                      float* __restrict__ out) {
    __shared__ short ylds[561 * 36];    // [pos][ci(32)+pad4] bf16 : 40392 B
    __shared__ short wlds[3 * 64 * 36]; // [tap_l][co(64)][ci(32)+pad4] : 13824 B

    int bx = blockIdx.x;
    int n = bx / 40;
    int r = bx % 40;
    int co0 = (r / 8) * 64;
    int sp = r % 8;
    int oh0 = (sp >> 1) * 8;
    int ow0 = (sp & 1) * 16;

    int tid = threadIdx.x;
    int lane = tid & 63;
    int wid = tid >> 6;
    int wm = wid >> 1, wn = wid & 1;
    int q = lane >> 4, lc = lane & 15;

    f32x4 acc[4][2];
#pragma unroll
    for (int i = 0; i < 4; ++i)
#pragma unroll
        for (int j = 0; j < 2; ++j) acc[i][j] = (f32x4){0.f, 0.f, 0.f, 0.f};

    const unsigned short* ytu = (const unsigned short*)yt;
    const unsigned short* wtu = (const unsigned short*)wtp;
    int ybase = ((n * HY + 2 * oh0) * HY + 2 * ow0) * CCH;

    for (int cc = 0; cc < 10; ++cc) {
        int ci0 = cc * 32;
        __syncthreads();  // previous iteration's compute done before overwrite
        // stage y tile: 561 positions x 32 ci (4 x 16B units per position)
        for (int u = tid; u < 2244; u += 256) {
            int p = u >> 2, s = u & 3;
            int pr = p / 33, pc = p % 33;
            const u32x4 gv = *(const u32x4*)(ytu + ybase + (pr * HY + pc) * CCH + ci0 + s * 8);
            u32x2* d = (u32x2*)(ylds + p * 36 + s * 8);
            d[0] = (u32x2){gv[0], gv[1]};
            d[1] = (u32x2){gv[2], gv[3]};
        }
#pragma unroll
        for (int gg = 0; gg < 3; ++gg) {
            if (gg) __syncthreads();  // previous tap-group compute done
            // stage 3 taps of w: [tap_l][co][ci]
            for (int u = tid; u < 768; u += 256) {
                int tl = u >> 8;
                int rr2 = u & 255;
                int co = rr2 >> 2, s = rr2 & 3;
                const u32x4 gv = *(const u32x4*)(wtu + ((gg * 3 + tl) * CCH + co0 + co) * CCH + ci0 + s * 8);
                u32x2* d = (u32x2*)(wlds + (tl * 64 + co) * 36 + s * 8);
                d[0] = (u32x2){gv[0], gv[1]};
                d[1] = (u32x2){gv[2], gv[3]};
            }
            __syncthreads();
#pragma unroll
            for (int tl = 0; tl < 3; ++tl) {
                int tap = gg * 3 + tl;
                int kh = tap / 3, kw = tap % 3;
                bf16x8_t af[4], bfr[2];
#pragma unroll
                for (int mf = 0; mf < 4; ++mf) {
                    // m = wm*64 + mf*16 + lc ; oh_l = wm*4+mf ; ow_l = lc
                    int p = (2 * (wm * 4 + mf) + kh) * 33 + (2 * lc + kw);
                    const s16x4* ap = (const s16x4*)(ylds + p * 36 + q * 8);
                    s16x4 a0 = ap[0], a1 = ap[1];
                    af[mf] = __builtin_shufflevector(a0, a1, 0, 1, 2, 3, 4, 5, 6, 7);
                }
#pragma unroll
                for (int nf = 0; nf < 2; ++nf) {
                    int co = wn * 32 + nf * 16 + lc;
                    const s16x4* bp = (const s16x4*)(wlds + (tl * 64 + co) * 36 + q * 8);
                    s16x4 b0 = bp[0], b1 = bp[1];
                    bfr[nf] = __builtin_shufflevector(b0, b1, 0, 1, 2, 3, 4, 5, 6, 7);
                }
#pragma unroll
                for (int mf = 0; mf < 4; ++mf)
#pragma unroll
                    for (int nf = 0; nf < 2; ++nf)
                        // arg0 = w-frag -> D rows = co ; arg1 = y-frag -> D cols = m
                        acc[mf][nf] = __builtin_amdgcn_mfma_f32_16x16x32_bf16(
                            bfr[nf], af[mf], acc[mf][nf], 0, 0, 0);
            }
        }
    }

    // epilogue: D[row=co][col=m]; row = q*4+reg, col = lc -> coalesced 64B segments
#pragma unroll
    for (int mf = 0; mf < 4; ++mf) {
        int oh = oh0 + wm * 4 + mf;
        int ow = ow0 + lc;
#pragma unroll
        for (int nf = 0; nf < 2; ++nf) {
#pragma unroll
            for (int rg = 0; rg < 4; ++rg) {
                int co = co0 + wn * 32 + nf * 16 + q * 4 + rg;
                out[((n * CCH + co) * 32 + oh) * 32 + ow] = acc[mf][nf][rg];
            }
        }
    }
}

// ---------------- Fallback: naive direct (correct, slow) ----------------
__global__ __launch_bounds__(256) void naive_kernel(const float* __restrict__ x,
                                                    const float* __restrict__ w,
                                                    const float* __restrict__ fk,
                                                    float* __restrict__ out) {
    int idx = blockIdx.x * 256 + threadIdx.x;
    if (idx >= NI * CCH * 32 * 32) return;
    int ow = idx & 31;
    int oh = (idx >> 5) & 31;
    int co = (idx >> 10) % CCH;
    int n = (idx >> 10) / CCH;
    float f0 = fk[0] + fk[1] + fk[2] + fk[3];
    float f1 = fk[4] + fk[5] + fk[6] + fk[7];
    float f2 = fk[8] + fk[9] + fk[10] + fk[11];
    float f3 = fk[12] + fk[13] + fk[14] + fk[15];
    float fv[4] = {f0, f1, f2, f3};
    float acc = 0.f;
    for (int ci = 0; ci < CCH; ++ci) {
        const float* xb = x + (size_t)(n * CCH + ci) * HW * HW;
        const float* wb = w + (size_t)(co * CCH + ci) * 9;
#pragma unroll
        for (int u = 0; u < 3; ++u) {
            int yr = 2 * oh + u;
#pragma unroll
            for (int v = 0; v < 3; ++v) {
                int yc = 2 * ow + v;
                float s = 0.f;
#pragma unroll
                for (int a = 0; a < 4; ++a) {
                    int xrw = yr - 2 + a;
                    if (xrw < 0 || xrw >= HW) continue;
                    float t = 0.f;
#pragma unroll
                    for (int b = 0; b < 4; ++b) {
                        int xc = yc - 2 + b;
                        if (xc >= 0 && xc < HW) t += fv[b] * xb[xrw * HW + xc];
                    }
                    s += fv[a] * t;
                }
                acc += wb[u * 3 + v] * s;
            }
        }
    }
    out[idx] = acc;
}

extern "C" void kernel_launch(void* const* d_in, const int* in_sizes, int n_in,
                              void* d_out, int out_size, void* d_ws, size_t ws_size,
                              hipStream_t stream) {
    const float* x = (const float*)d_in[0];
    const float* w = (const float*)d_in[1];
    const float* fk = (const float*)d_in[2];
    float* out = (float*)d_out;

    const size_t ybytes = (size_t)NI * HY * HY * CCH * 2;  // 43,264,000 (16-aligned)
    const size_t wtoff = ybytes;
    const size_t need = wtoff + (size_t)9 * CCH * CCH * 2;  // +1,843,200 = 45,107,200

    if (ws_size >= need) {
        __hip_bfloat16* yt = (__hip_bfloat16*)d_ws;
        __hip_bfloat16* wt = (__hip_bfloat16*)((char*)d_ws + wtoff);
        fir_kernel<<<16 * 9 * 20, 256, 0, stream>>>(x, fk, yt);
        wt_kernel<<<(9 * CCH * CCH + 255) / 256, 256, 0, stream>>>(w, wt);
        conv_kernel<<<16 * 8 * 5, 256, 0, stream>>>(yt, wt, out);
    } else {
        naive_kernel<<<(NI * CCH * 32 * 32 + 255) / 256, 256, 0, stream>>>(x, w, fk, out);
    }
}

// Round 2
// 148.554 us; speedup vs baseline: 1.1136x; 1.1136x over previous
//
#include <hip/hip_runtime.h>
#include <hip/hip_bf16.h>

// FirDownsample: y = depthwise FIR(4x4 separable [1,3,3,1]) on x (pad 2),
// out = conv3x3(y, w), stride 2.  x:(16,320,64,64) f32, out:(16,320,32,32) f32.
//
// R2: conv reads BOTH MFMA operands directly from global (no LDS, no barriers).
//   K1 fir_kernel : x -> y_t[n][65][65][320] bf16 (channels-last; frag loads coalesce)
//   K2 wt2_kernel : w -> wt2[tap][cc][q][co][8ci] bf16 (B-frags 256B-contiguous)
//   K3 conv_kernel: dataflow MFMA, 640 blocks all co-resident, latency hidden by TLP.

typedef short bf16x8_t __attribute__((ext_vector_type(8)));
typedef float f32x4 __attribute__((ext_vector_type(4)));

#define NI 16
#define CCH 320
#define HW 64
#define HY 65

// ---------------- K1: separable FIR, x(f32) -> y_t bf16 [n][r][c][ci] ----------------
__global__ __launch_bounds__(256) void fir_kernel(const float* __restrict__ x,
                                                  const float* __restrict__ fir_k,
                                                  __hip_bfloat16* __restrict__ yt) {
    __shared__ float vlds[8 * 68 * 17];  // [j][cc][ci+pad]
    int bx = blockIdx.x;
    int n   = bx / 180;
    int rr  = bx % 180;
    int r0  = (rr / 20) * 8;
    int ci0 = (rr % 20) * 16;

    float f0 = fir_k[0] + fir_k[1] + fir_k[2] + fir_k[3];
    float f1 = fir_k[4] + fir_k[5] + fir_k[6] + fir_k[7];
    float f2 = fir_k[8] + fir_k[9] + fir_k[10] + fir_k[11];
    float f3 = fir_k[12] + fir_k[13] + fir_k[14] + fir_k[15];

    int tid = threadIdx.x;
    int lane = tid & 63;
    int g = tid >> 6;

    for (int cis = g; cis < 16; cis += 4) {
        int ci = ci0 + cis;
        const float* xb = x + (size_t)(n * CCH + ci) * HW * HW;
        float xr[11];
#pragma unroll
        for (int jr = 0; jr < 11; ++jr) {
            int row = r0 + jr - 2;
            xr[jr] = (row >= 0 && row < HW) ? xb[row * HW + lane] : 0.f;
        }
#pragma unroll
        for (int j = 0; j < 8; ++j) {
            float v = f0 * xr[j] + f1 * xr[j + 1] + f2 * xr[j + 2] + f3 * xr[j + 3];
            vlds[(j * 68 + lane + 2) * 17 + cis] = v;
            if (lane < 2)   vlds[(j * 68 + lane) * 17 + cis] = 0.f;
            if (lane >= 62) vlds[(j * 68 + lane + 4) * 17 + cis] = 0.f;
        }
    }
    __syncthreads();

    int cis = tid & 15;
    int cl  = tid >> 4;
#pragma unroll
    for (int j = 0; j < 8; ++j) {
        if (r0 + j >= HY) break;
        for (int cb = 0; cb < 5; ++cb) {
            int c = cb * 16 + cl;
            if (c < HY) {
                float yv = f0 * vlds[(j * 68 + c) * 17 + cis]
                         + f1 * vlds[(j * 68 + c + 1) * 17 + cis]
                         + f2 * vlds[(j * 68 + c + 2) * 17 + cis]
                         + f3 * vlds[(j * 68 + c + 3) * 17 + cis];
                yt[(size_t)((n * HY + r0 + j) * HY + c) * CCH + ci0 + cis] =
                    __float2bfloat16(yv);
            }
        }
    }
}

// ---------------- K2: w (co,ci,3,3) f32 -> wt2[tap][cc][q][co][8] bf16 ----------------
__global__ __launch_bounds__(256) void wt2_kernel(const float* __restrict__ w,
                                                  __hip_bfloat16* __restrict__ wt) {
    int idx = blockIdx.x * 256 + threadIdx.x;
    if (idx < 9 * CCH * CCH) {
        int j  = idx & 7;
        int co = (idx >> 3) % CCH;
        int t2 = idx / 2560;          // tap*40 + cc*4 + q
        int q  = t2 & 3;
        int cc = (t2 >> 2) % 10;
        int tap = t2 / 40;
        int ci = cc * 32 + q * 8 + j;
        wt[idx] = __float2bfloat16(w[(co * CCH + ci) * 9 + tap]);
    }
}

// ---------------- K3: dataflow MFMA conv (no LDS, no barriers) ----------------
// block: n, co-chunk 64, spatial 8(oh) x 16(ow) = 128 m. 4 waves = 2(wm) x 2(wn).
// Per cc (32 ci), per tap: 4 A-frags + 2 B-frags from global, 8 MFMA.
__global__ __launch_bounds__(256, 4) void conv_kernel(const __hip_bfloat16* __restrict__ yt,
                                                      const __hip_bfloat16* __restrict__ wt2,
                                                      float* __restrict__ out) {
    int bx = blockIdx.x;
    int n = bx / 40;
    int r = bx % 40;
    int co0 = (r / 8) * 64;
    int sp = r % 8;
    int oh0 = (sp >> 1) * 8;
    int ow0 = (sp & 1) * 16;

    int tid = threadIdx.x;
    int lane = tid & 63;
    int wid = tid >> 6;
    int wm = wid >> 1, wn = wid & 1;
    int q = lane >> 4, lc = lane & 15;

    f32x4 acc[4][2];
#pragma unroll
    for (int i = 0; i < 4; ++i)
#pragma unroll
        for (int j = 0; j < 2; ++j) acc[i][j] = (f32x4){0.f, 0.f, 0.f, 0.f};

    const unsigned short* ytu = (const unsigned short*)yt;
    const unsigned short* wtu = (const unsigned short*)wt2;

    // per-lane bases (in shorts); 16B-aligned loads throughout
    const unsigned short* ybl = ytu + (size_t)((n * HY + 2 * oh0) * HY + 2 * ow0 + 2 * lc) * CCH + q * 8;
    const unsigned short* wbl = wtu + (size_t)q * 2560 + (size_t)(co0 + wn * 32 + lc) * 8;

    for (int cc = 0; cc < 10; ++cc) {
#pragma unroll
        for (int tap = 0; tap < 9; ++tap) {
            const int kh = tap / 3, kw = tap % 3;
            bf16x8_t af[4], bfr[2];
#pragma unroll
            for (int mf = 0; mf < 4; ++mf) {
                // y position row (local) = 8*wm + 2*mf + kh, col += kw
                const int off = ((8 * wm + 2 * mf + kh) * HY + kw) * CCH;
                af[mf] = *(const bf16x8_t*)(ybl + off);
            }
#pragma unroll
            for (int nf = 0; nf < 2; ++nf) {
                bfr[nf] = *(const bf16x8_t*)(wbl + tap * 102400 + nf * 128);
            }
#pragma unroll
            for (int mf = 0; mf < 4; ++mf)
#pragma unroll
                for (int nf = 0; nf < 2; ++nf)
                    // arg0 = w-frag -> D rows = co ; arg1 = y-frag -> D cols = m
                    acc[mf][nf] = __builtin_amdgcn_mfma_f32_16x16x32_bf16(
                        bfr[nf], af[mf], acc[mf][nf], 0, 0, 0);
        }
        ybl += 32;      // next 32 ci in channels-last y
        wbl += 10240;   // next cc slab in wt2
    }

    // epilogue: D[row=co][col=m]; coalesced 64B segments
#pragma unroll
    for (int mf = 0; mf < 4; ++mf) {
        int oh = oh0 + wm * 4 + mf;
        int ow = ow0 + lc;
#pragma unroll
        for (int nf = 0; nf < 2; ++nf) {
#pragma unroll
            for (int rg = 0; rg < 4; ++rg) {
                int co = co0 + wn * 32 + nf * 16 + q * 4 + rg;
                out[((n * CCH + co) * 32 + oh) * 32 + ow] = acc[mf][nf][rg];
            }
        }
    }
}

// ---------------- Fallback: naive direct (correct, slow) ----------------
__global__ __launch_bounds__(256) void naive_kernel(const float* __restrict__ x,
                                                    const float* __restrict__ w,
                                                    const float* __restrict__ fk,
                                                    float* __restrict__ out) {
    int idx = blockIdx.x * 256 + threadIdx.x;
    if (idx >= NI * CCH * 32 * 32) return;
    int ow = idx & 31;
    int oh = (idx >> 5) & 31;
    int co = (idx >> 10) % CCH;
    int n = (idx >> 10) / CCH;
    float f0 = fk[0] + fk[1] + fk[2] + fk[3];
    float f1 = fk[4] + fk[5] + fk[6] + fk[7];
    float f2 = fk[8] + fk[9] + fk[10] + fk[11];
    float f3 = fk[12] + fk[13] + fk[14] + fk[15];
    float fv[4] = {f0, f1, f2, f3};
    float acc = 0.f;
    for (int ci = 0; ci < CCH; ++ci) {
        const float* xb = x + (size_t)(n * CCH + ci) * HW * HW;
        const float* wb = w + (size_t)(co * CCH + ci) * 9;
#pragma unroll
        for (int u = 0; u < 3; ++u) {
            int yr = 2 * oh + u;
#pragma unroll
            for (int v = 0; v < 3; ++v) {
                int yc = 2 * ow + v;
                float s = 0.f;
#pragma unroll
                for (int a = 0; a < 4; ++a) {
                    int xrw = yr - 2 + a;
                    if (xrw < 0 || xrw >= HW) continue;
                    float t = 0.f;
#pragma unroll
                    for (int b = 0; b < 4; ++b) {
                        int xc = yc - 2 + b;
                        if (xc >= 0 && xc < HW) t += fv[b] * xb[xrw * HW + xc];
                    }
                    s += fv[a] * t;
                }
                acc += wb[u * 3 + v] * s;
            }
        }
    }
    out[idx] = acc;
}

extern "C" void kernel_launch(void* const* d_in, const int* in_sizes, int n_in,
                              void* d_out, int out_size, void* d_ws, size_t ws_size,
                              hipStream_t stream) {
    const float* x = (const float*)d_in[0];
    const float* w = (const float*)d_in[1];
    const float* fk = (const float*)d_in[2];
    float* out = (float*)d_out;

    const size_t ybytes = (size_t)NI * HY * HY * CCH * 2;     // 43,264,000 (16-aligned)
    const size_t wtoff = ybytes;
    const size_t need = wtoff + (size_t)9 * CCH * CCH * 2;    // 45,107,200

    if (ws_size >= need) {
        __hip_bfloat16* yt = (__hip_bfloat16*)d_ws;
        __hip_bfloat16* wt = (__hip_bfloat16*)((char*)d_ws + wtoff);
        fir_kernel<<<16 * 9 * 20, 256, 0, stream>>>(x, fk, yt);
        wt2_kernel<<<(9 * CCH * CCH + 255) / 256, 256, 0, stream>>>(w, wt);
        conv_kernel<<<16 * 8 * 5, 256, 0, stream>>>(yt, wt, out);
    } else {
        naive_kernel<<<(NI * CCH * 32 * 32 + 255) / 256, 256, 0, stream>>>(x, w, fk, out);
    }
}

// Round 3
// 102.788 us; speedup vs baseline: 1.6094x; 1.4452x over previous
//
#include <hip/hip_runtime.h>
#include <hip/hip_bf16.h>

// FirDownsample: y = depthwise FIR(4x4 separable [1,3,3,1]) on x (pad 2),
// out = conv3x3(y, w), stride 2.  x:(16,320,64,64) f32, out:(16,320,32,32) f32.
//
// R3: conv stages the y-tile in LDS (conflict-free 80B-padded rows, linear addrs),
// reads tap fragments from LDS instead of 9x from L1. y layout now ci-chunk-major:
//   K1 fir_kernel : x -> y[n][cc=10][65][65][32ci] bf16
//   K2 wt2_kernel : w -> wt2[tap][cc][q][co][8ci] bf16
//   K3 conv_kernel: M64xN64 block, 4 waves (M32xN32), LDS-staged A, global B,
//                   reg-staged next-tile prefetch (T14), 2 barriers/cc.

typedef short bf16x8_t __attribute__((ext_vector_type(8)));
typedef float f32x4 __attribute__((ext_vector_type(4)));
typedef unsigned int u32x4 __attribute__((ext_vector_type(4)));

#define NI 16
#define CCH 320
#define HW 64
#define HY 65
#define HY2 4225           // 65*65
#define CCSTEP 135200      // 4225*32 shorts per cc-plane

// ---------------- K1: separable FIR, x(f32) -> y bf16 [n][cc][r][c][32] ----------------
__global__ __launch_bounds__(256) void fir_kernel(const float* __restrict__ x,
                                                  const float* __restrict__ fir_k,
                                                  __hip_bfloat16* __restrict__ yt) {
    __shared__ float vlds[8 * 68 * 17];  // [j][cc][ci+pad]
    int bx = blockIdx.x;
    int n   = bx / 180;
    int rr  = bx % 180;
    int r0  = (rr / 20) * 8;
    int ci0 = (rr % 20) * 16;

    float f0 = fir_k[0] + fir_k[1] + fir_k[2] + fir_k[3];
    float f1 = fir_k[4] + fir_k[5] + fir_k[6] + fir_k[7];
    float f2 = fir_k[8] + fir_k[9] + fir_k[10] + fir_k[11];
    float f3 = fir_k[12] + fir_k[13] + fir_k[14] + fir_k[15];

    int tid = threadIdx.x;
    int lane = tid & 63;
    int g = tid >> 6;

    for (int cis = g; cis < 16; cis += 4) {
        int ci = ci0 + cis;
        const float* xb = x + (size_t)(n * CCH + ci) * HW * HW;
        float xr[11];
#pragma unroll
        for (int jr = 0; jr < 11; ++jr) {
            int row = r0 + jr - 2;
            xr[jr] = (row >= 0 && row < HW) ? xb[row * HW + lane] : 0.f;
        }
#pragma unroll
        for (int j = 0; j < 8; ++j) {
            float v = f0 * xr[j] + f1 * xr[j + 1] + f2 * xr[j + 2] + f3 * xr[j + 3];
            vlds[(j * 68 + lane + 2) * 17 + cis] = v;
            if (lane < 2)   vlds[(j * 68 + lane) * 17 + cis] = 0.f;
            if (lane >= 62) vlds[(j * 68 + lane + 4) * 17 + cis] = 0.f;
        }
    }
    __syncthreads();

    int cis = tid & 15;
    int cl  = tid >> 4;
    int ci  = ci0 + cis;
    size_t obase = (size_t)(n * 10 + (ci >> 5)) * HY2 * 32 + (ci & 31);
#pragma unroll
    for (int j = 0; j < 8; ++j) {
        if (r0 + j >= HY) break;
        for (int cb = 0; cb < 5; ++cb) {
            int c = cb * 16 + cl;
            if (c < HY) {
                float yv = f0 * vlds[(j * 68 + c) * 17 + cis]
                         + f1 * vlds[(j * 68 + c + 1) * 17 + cis]
                         + f2 * vlds[(j * 68 + c + 2) * 17 + cis]
                         + f3 * vlds[(j * 68 + c + 3) * 17 + cis];
                yt[obase + (size_t)((r0 + j) * HY + c) * 32] = __float2bfloat16(yv);
            }
        }
    }
}

// ---------------- K2: w (co,ci,3,3) f32 -> wt2[tap][cc][q][co][8] bf16 ----------------
__global__ __launch_bounds__(256) void wt2_kernel(const float* __restrict__ w,
                                                  __hip_bfloat16* __restrict__ wt) {
    int idx = blockIdx.x * 256 + threadIdx.x;
    if (idx < 9 * CCH * CCH) {
        int j  = idx & 7;
        int co = (idx >> 3) % CCH;
        int t2 = idx / 2560;          // tap*40 + cc*4 + q
        int q  = t2 & 3;
        int cc = (t2 >> 2) % 10;
        int tap = t2 / 40;
        int ci = cc * 32 + q * 8 + j;
        wt[idx] = __float2bfloat16(w[(co * CCH + ci) * 9 + tap]);
    }
}

// ---------------- K3: LDS-staged MFMA conv ----------------
// grid = (n*5 + cb)*16 + sp ; block tile M64 (4oh x 16ow) x N64 co; 4 waves M32xN32.
// LDS: 297 positions (9r x 33c) x 32ci, rows padded to 80B -> conflict-free b128 reads.
__global__ __launch_bounds__(256, 3) void conv_kernel(const __hip_bfloat16* __restrict__ yt,
                                                      const __hip_bfloat16* __restrict__ wt2,
                                                      float* __restrict__ out) {
    __shared__ short ylds[1485 * 8];   // 23,760 B ; 16B-unit u at ylds[u*8]; row p = units 5p..5p+3 (+pad)

    int bx = blockIdx.x;
    int sp = bx & 15;
    int t  = bx >> 4;
    int cb = t % 5;
    int n  = t / 5;
    int co0 = cb * 64;
    int oh0 = (sp >> 1) * 4;
    int ow0 = (sp & 1) * 16;

    int tid = threadIdx.x;
    int lane = tid & 63;
    int wid = tid >> 6;
    int wm = wid >> 1, wn = wid & 1;
    int q = lane >> 4, lc = lane & 15;

    const unsigned short* ytu = (const unsigned short*)yt;
    const unsigned short* wtu = (const unsigned short*)wt2;

    // staging source offsets (shorts), cc=0; per-cc add CCSTEP
    int ybase = (n * 10 * HY2 + (2 * oh0) * HY + 2 * ow0) * 32;
    int goff[6];
    bool gv[6];
#pragma unroll
    for (int k = 0; k < 6; ++k) {
        int u = k * 256 + tid;
        gv[k] = (u < 1485);
        int uc = gv[k] ? u : 1484;
        int p = uc / 5, s = uc - p * 5;
        if (s == 4) s = 3;                 // pad unit: load a safe dup, never read
        int pr = p / 33, pc = p - pr * 33;
        goff[k] = ybase + (pr * HY + pc) * 32 + s * 8;
    }

    const unsigned short* wbl = wtu + q * 2560 + (size_t)(co0 + wn * 32 + lc) * 8;
    const short* abase = ylds + (4 * wm * 33 + 2 * lc) * 40 + q * 8;

    f32x4 acc[2][2];
#pragma unroll
    for (int i = 0; i < 2; ++i)
#pragma unroll
        for (int j = 0; j < 2; ++j) acc[i][j] = (f32x4){0.f, 0.f, 0.f, 0.f};

    // prologue: prefetch stage regs for cc=0
    u32x4 stg[6];
#pragma unroll
    for (int k = 0; k < 6; ++k)
        if (gv[k]) stg[k] = *(const u32x4*)(ytu + goff[k]);

    for (int cc = 0; cc < 10; ++cc) {
        __syncthreads();                       // (1) prev reads of ylds done
#pragma unroll
        for (int k = 0; k < 6; ++k)
            if (gv[k]) *(u32x4*)(ylds + (k * 256 + tid) * 8) = stg[k];
        __syncthreads();                       // (2) writes visible (vmem queue empty -> cheap)

        const unsigned short* wcc = wbl + cc * 10240;
        // B frags for kw=0 (issued first in vmem queue)
        bf16x8_t b0[3][2];
#pragma unroll
        for (int kh = 0; kh < 3; ++kh)
#pragma unroll
            for (int nf = 0; nf < 2; ++nf)
                b0[kh][nf] = *(const bf16x8_t*)(wcc + (kh * 3 + 0) * 102400 + nf * 128);
        // next-tile stage prefetch: in flight across the whole compute phase
        if (cc < 9) {
#pragma unroll
            for (int k = 0; k < 6; ++k)
                if (gv[k]) stg[k] = *(const u32x4*)(ytu + goff[k] + (cc + 1) * CCSTEP);
        }

        // ---- kw = 0 ----
        bf16x8_t af[5];
#pragma unroll
        for (int rl = 0; rl < 5; ++rl)
            af[rl] = *(const bf16x8_t*)(abase + (rl * 33 + 0) * 40);
        bf16x8_t b1[3][2];
#pragma unroll
        for (int kh = 0; kh < 3; ++kh)
#pragma unroll
            for (int nf = 0; nf < 2; ++nf)
                b1[kh][nf] = *(const bf16x8_t*)(wcc + (kh * 3 + 1) * 102400 + nf * 128);
#pragma unroll
        for (int kh = 0; kh < 3; ++kh)
#pragma unroll
            for (int mf = 0; mf < 2; ++mf)
#pragma unroll
                for (int nf = 0; nf < 2; ++nf)
                    acc[mf][nf] = __builtin_amdgcn_mfma_f32_16x16x32_bf16(
                        b0[kh][nf], af[2 * mf + kh], acc[mf][nf], 0, 0, 0);

        // ---- kw = 1 ----
#pragma unroll
        for (int rl = 0; rl < 5; ++rl)
            af[rl] = *(const bf16x8_t*)(abase + (rl * 33 + 1) * 40);
        bf16x8_t b2[3][2];
#pragma unroll
        for (int kh = 0; kh < 3; ++kh)
#pragma unroll
            for (int nf = 0; nf < 2; ++nf)
                b2[kh][nf] = *(const bf16x8_t*)(wcc + (kh * 3 + 2) * 102400 + nf * 128);
#pragma unroll
        for (int kh = 0; kh < 3; ++kh)
#pragma unroll
            for (int mf = 0; mf < 2; ++mf)
#pragma unroll
                for (int nf = 0; nf < 2; ++nf)
                    acc[mf][nf] = __builtin_amdgcn_mfma_f32_16x16x32_bf16(
                        b1[kh][nf], af[2 * mf + kh], acc[mf][nf], 0, 0, 0);

        // ---- kw = 2 ----
#pragma unroll
        for (int rl = 0; rl < 5; ++rl)
            af[rl] = *(const bf16x8_t*)(abase + (rl * 33 + 2) * 40);
#pragma unroll
        for (int kh = 0; kh < 3; ++kh)
#pragma unroll
            for (int mf = 0; mf < 2; ++mf)
#pragma unroll
                for (int nf = 0; nf < 2; ++nf)
                    acc[mf][nf] = __builtin_amdgcn_mfma_f32_16x16x32_bf16(
                        b2[kh][nf], af[2 * mf + kh], acc[mf][nf], 0, 0, 0);
    }

    // epilogue: D[row=co][col=m]; coalesced 64B segments
#pragma unroll
    for (int mf = 0; mf < 2; ++mf) {
        int oh = oh0 + wm * 2 + mf;
        int ow = ow0 + lc;
#pragma unroll
        for (int nf = 0; nf < 2; ++nf) {
#pragma unroll
            for (int rg = 0; rg < 4; ++rg) {
                int co = co0 + wn * 32 + nf * 16 + q * 4 + rg;
                out[((n * CCH + co) * 32 + oh) * 32 + ow] = acc[mf][nf][rg];
            }
        }
    }
}

// ---------------- Fallback: naive direct (correct, slow) ----------------
__global__ __launch_bounds__(256) void naive_kernel(const float* __restrict__ x,
                                                    const float* __restrict__ w,
                                                    const float* __restrict__ fk,
                                                    float* __restrict__ out) {
    int idx = blockIdx.x * 256 + threadIdx.x;
    if (idx >= NI * CCH * 32 * 32) return;
    int ow = idx & 31;
    int oh = (idx >> 5) & 31;
    int co = (idx >> 10) % CCH;
    int n = (idx >> 10) / CCH;
    float f0 = fk[0] + fk[1] + fk[2] + fk[3];
    float f1 = fk[4] + fk[5] + fk[6] + fk[7];
    float f2 = fk[8] + fk[9] + fk[10] + fk[11];
    float f3 = fk[12] + fk[13] + fk[14] + fk[15];
    float fv[4] = {f0, f1, f2, f3};
    float acc = 0.f;
    for (int ci = 0; ci < CCH; ++ci) {
        const float* xb = x + (size_t)(n * CCH + ci) * HW * HW;
        const float* wb = w + (size_t)(co * CCH + ci) * 9;
#pragma unroll
        for (int u = 0; u < 3; ++u) {
            int yr = 2 * oh + u;
#pragma unroll
            for (int v = 0; v < 3; ++v) {
                int yc = 2 * ow + v;
                float s = 0.f;
#pragma unroll
                for (int a = 0; a < 4; ++a) {
                    int xrw = yr - 2 + a;
                    if (xrw < 0 || xrw >= HW) continue;
                    float t = 0.f;
#pragma unroll
                    for (int b = 0; b < 4; ++b) {
                        int xc = yc - 2 + b;
                        if (xc >= 0 && xc < HW) t += fv[b] * xb[xrw * HW + xc];
                    }
                    s += fv[a] * t;
                }
                acc += wb[u * 3 + v] * s;
            }
        }
    }
    out[idx] = acc;
}

extern "C" void kernel_launch(void* const* d_in, const int* in_sizes, int n_in,
                              void* d_out, int out_size, void* d_ws, size_t ws_size,
                              hipStream_t stream) {
    const float* x = (const float*)d_in[0];
    const float* w = (const float*)d_in[1];
    const float* fk = (const float*)d_in[2];
    float* out = (float*)d_out;

    const size_t ybytes = (size_t)NI * 10 * HY2 * 32 * 2;     // 43,264,000
    const size_t wtoff = ybytes;
    const size_t need = wtoff + (size_t)9 * CCH * CCH * 2;    // 45,107,200

    if (ws_size >= need) {
        __hip_bfloat16* yt = (__hip_bfloat16*)d_ws;
        __hip_bfloat16* wt = (__hip_bfloat16*)((char*)d_ws + wtoff);
        fir_kernel<<<16 * 9 * 20, 256, 0, stream>>>(x, fk, yt);
        wt2_kernel<<<(9 * CCH * CCH + 255) / 256, 256, 0, stream>>>(w, wt);
        conv_kernel<<<16 * 5 * 16, 256, 0, stream>>>(yt, wt, out);
    } else {
        naive_kernel<<<(NI * CCH * 32 * 32 + 255) / 256, 256, 0, stream>>>(x, w, fk, out);
    }
}